// Round 9
// baseline (537.412 us; speedup 1.0000x reference)
//
#include <hip/hip_runtime.h>

#define NN 100000
#define NE 1600000

#define EBLK 4096
#define NBLK 391            // ceil(NE/EBLK)
#define NBUCK 196           // ceil(NN/512), bucket = dst>>9
#define CSTRIDE ((size_t)NN * 8)   // uint stride of one 16-channel chunk

typedef unsigned int uint32;
typedef __attribute__((ext_vector_type(8))) short bf16x8;
typedef __attribute__((ext_vector_type(4))) float f32x4;

__device__ inline unsigned short f2bf(float f) {
    uint32 u = __float_as_uint(f);
    u += 0x7FFFu + ((u >> 16) & 1u);      // round to nearest even
    return (unsigned short)(u >> 16);
}
__device__ inline float bflo(uint32 v) { return __uint_as_float(v << 16); }
__device__ inline float bfhi(uint32 v) { return __uint_as_float(v & 0xFFFF0000u); }

__device__ inline int wave_incl_scan(int v) {   // 64-lane inclusive scan
#pragma unroll
    for (int d = 1; d < 64; d <<= 1) {
        int u = __shfl_up(v, d, 64);
        if ((threadIdx.x & 63) >= (unsigned)d) v += u;
    }
    return v;
}

// ---------------- CSR build, atomic-free (bucketed) ----------------

__global__ __launch_bounds__(256) void p1_hist_k(const int* __restrict__ dst,
                                                 int* __restrict__ histT) {
    __shared__ int h[256];
    int t = threadIdx.x;
    h[t] = 0;
    __syncthreads();
    int e0 = blockIdx.x * EBLK;
#pragma unroll
    for (int i = 0; i < EBLK / 256; ++i) {
        int e = e0 + i * 256 + t;
        if (e < NE) atomicAdd(&h[dst[e] >> 9], 1);
    }
    __syncthreads();
    histT[t * NBLK + blockIdx.x] = h[t];   // histT[bucket][blk]
}

__global__ __launch_bounds__(256) void p2a_k(const int* __restrict__ histT,
                                             int* __restrict__ boff2,
                                             int* __restrict__ btot) {
    __shared__ int ws[4];
    __shared__ int ws2[4];
    int b = blockIdx.x, t = threadIdx.x;
    const int* row = histT + (size_t)b * NBLK;
    int v0 = row[t];
    int i0 = wave_incl_scan(v0);
    if ((t & 63) == 63) ws[t >> 6] = i0;
    __syncthreads();
    int add = 0;
    for (int w = 0; w < (t >> 6); ++w) add += ws[w];
    boff2[(size_t)b * NBLK + t] = i0 - v0 + add;
    int tot0 = ws[0] + ws[1] + ws[2] + ws[3];
    int idx = 256 + t;
    int v1 = (idx < NBLK) ? row[idx] : 0;
    int i1 = wave_incl_scan(v1);
    if ((t & 63) == 63) ws2[t >> 6] = i1;
    __syncthreads();
    int add2 = 0;
    for (int w = 0; w < (t >> 6); ++w) add2 += ws2[w];
    if (idx < NBLK) boff2[(size_t)b * NBLK + idx] = tot0 + i1 - v1 + add2;
    if (t == 0) btot[b] = tot0 + ws2[0] + ws2[1] + ws2[2] + ws2[3];
}

__global__ __launch_bounds__(256) void p2b_k(const int* __restrict__ btot,
                                             int* __restrict__ bucket_base,
                                             int* __restrict__ offs) {
    __shared__ int ws[4];
    int t = threadIdx.x;
    int v = btot[t];
    int incl = wave_incl_scan(v);
    if ((t & 63) == 63) ws[t >> 6] = incl;
    __syncthreads();
    int add = 0;
    for (int w = 0; w < (t >> 6); ++w) add += ws[w];
    int excl = incl - v + add;
    bucket_base[t] = excl;
    if (t == 255) bucket_base[256] = excl + v;   // == NE
    if (t == 0) offs[NN] = NE;
}

__global__ __launch_bounds__(256) void p3_scatter_k(const int* __restrict__ src,
                                                    const int* __restrict__ dst,
                                                    const int* __restrict__ boff2,
                                                    const int* __restrict__ bucket_base,
                                                    uint32* __restrict__ ebuf) {
    __shared__ int cur[256];
    int t = threadIdx.x;
    cur[t] = bucket_base[t] + boff2[(size_t)t * NBLK + blockIdx.x];
    __syncthreads();
    int e0 = blockIdx.x * EBLK;
#pragma unroll
    for (int i = 0; i < EBLK / 256; ++i) {
        int e = e0 + i * 256 + t;
        if (e < NE) {
            int d = dst[e];
            int pos = atomicAdd(&cur[d >> 9], 1);      // LDS atomic
            ebuf[pos] = ((uint32)(d & 511) << 17) | (uint32)src[e];
        }
    }
}

__global__ __launch_bounds__(256) void p4_csr_k(const uint32* __restrict__ ebuf,
                                                const int* __restrict__ bucket_base,
                                                int* __restrict__ offs,
                                                float* __restrict__ dinv,
                                                int* __restrict__ csrc) {
    __shared__ int cntL[512];
    __shared__ int offL[512];
    __shared__ int wsum[4];
    int t = threadIdx.x;
    int bbase = bucket_base[blockIdx.x];
    int bend  = bucket_base[blockIdx.x + 1];
    cntL[t] = 0; cntL[t + 256] = 0;
    __syncthreads();
    for (int e = bbase + t; e < bend; e += 256)
        atomicAdd(&cntL[ebuf[e] >> 17], 1);
    __syncthreads();
    int c0 = cntL[2 * t], c1 = cntL[2 * t + 1];
    int ps = c0 + c1;
    int incl = wave_incl_scan(ps);
    if ((t & 63) == 63) wsum[t >> 6] = incl;
    __syncthreads();
    int add = 0;
    for (int w = 0; w < (t >> 6); ++w) add += wsum[w];
    int excl = incl - ps + add;
    offL[2 * t] = excl;
    offL[2 * t + 1] = excl + c0;
    int n0 = blockIdx.x * 512;
#pragma unroll
    for (int j = 0; j < 2; ++j) {
        int dl = 2 * t + j;
        int node = n0 + dl;
        if (node < NN) {
            offs[node] = bbase + offL[dl];
            dinv[node] = rsqrtf((float)(cntL[dl] + 1));
        }
    }
    __syncthreads();
    cntL[2 * t] = offL[2 * t];          // reuse as cursors
    cntL[2 * t + 1] = offL[2 * t + 1];
    __syncthreads();
    for (int e = bbase + t; e < bend; e += 256) {
        uint32 v = ebuf[e];
        int pos = atomicAdd(&cntL[v >> 17], 1);   // LDS atomic
        csrc[bbase + pos] = (int)(v & 0x1FFFFu);
    }
}

// -------- W prep: Wt[col][k] bf16-packed (uint = 2 consecutive k) --------

__global__ __launch_bounds__(256) void wprep_k(const float* __restrict__ W,
                                               uint32* __restrict__ Wt) {
    int id = blockIdx.x * 256 + threadIdx.x;   // 8192 uints
    int col = id >> 6, ku = id & 63;
    float a = W[(2 * ku) * 128 + col];
    float b = W[(2 * ku + 1) * 128 + col];
    Wt[id] = (uint32)f2bf(a) | ((uint32)f2bf(b) << 16);
}

// ---------------- MFMA GEMM: HS = dinv * act(X) @ W, chunked bf16 ----------
// Output layout: chunk c (16 ch) at HS[c*NN*8 + row*8 + u] (u = uint in chunk).
// AFF=0: X f32 [N,128].  AFF=1: X packed bf16, apply relu(sc*x+sh) on load.
// Block: 256 thr / 4 waves, tile 64 rows x 128 cols, K=128 in 4 steps of 32.

template <int AFF>
__global__ __launch_bounds__(256) void gemm_k(const void* __restrict__ Xv,
                                              const uint32* __restrict__ Wt,
                                              const float* __restrict__ par,
                                              const float* __restrict__ dinv,
                                              uint32* __restrict__ HS) {
    __shared__ __align__(16) char lds[52224];
    const int APITCH = 272;               // bytes per A/B row (136 bf16)
    char* Ab = lds;
    char* Bb = lds + 17408;
    int t = threadIdx.x;
    int row0 = blockIdx.x * 64;

    // stage Bt: 128 rows x 16 uint4
    {
        uint4* src = (uint4*)Wt;
#pragma unroll
        for (int i = 0; i < 8; ++i) {
            int idx4 = i * 256 + t;          // 2048 uint4
            int r = idx4 >> 4, cu = idx4 & 15;
            *(uint4*)(Bb + r * APITCH + cu * 16) = src[r * 16 + cu];
        }
    }
    // stage A: 64 rows x 128 bf16
#pragma unroll
    for (int i = 0; i < 8; ++i) {
        int idx = i * 256 + t;               // 2048 quads of channels
        int r = idx >> 5, c4 = idx & 31;
        int row = row0 + r;
        float4 v = make_float4(0.f, 0.f, 0.f, 0.f);
        if (row < NN) {
            if (AFF) {
                uint2 u = *((const uint2*)((const uint32*)Xv + (size_t)row * 64) + c4);
                v.x = bflo(u.x); v.y = bfhi(u.x);
                v.z = bflo(u.y); v.w = bfhi(u.y);
                int c = c4 * 4;
                v.x = fmaxf(0.f, fmaf(par[c + 0], v.x, par[128 + c + 0]));
                v.y = fmaxf(0.f, fmaf(par[c + 1], v.y, par[128 + c + 1]));
                v.z = fmaxf(0.f, fmaf(par[c + 2], v.z, par[128 + c + 2]));
                v.w = fmaxf(0.f, fmaf(par[c + 3], v.w, par[128 + c + 3]));
            } else {
                v = *((const float4*)((const float*)Xv + (size_t)row * 128) + c4);
            }
        }
        uint32 o0 = (uint32)f2bf(v.x) | ((uint32)f2bf(v.y) << 16);
        uint32 o1 = (uint32)f2bf(v.z) | ((uint32)f2bf(v.w) << 16);
        uint2 o; o.x = o0; o.y = o1;
        *(uint2*)(Ab + r * APITCH + c4 * 8) = o;
    }
    __syncthreads();

    int w = t >> 6, lane = t & 63;
    int l15 = lane & 15, l4 = lane >> 4;
    const char* aptr = Ab + (w * 16 + l15) * APITCH + l4 * 16;
    const char* bptr = Bb + l15 * APITCH + l4 * 16;
    f32x4 acc[8];
#pragma unroll
    for (int n = 0; n < 8; ++n)
#pragma unroll
        for (int j = 0; j < 4; ++j) acc[n][j] = 0.f;

#pragma unroll
    for (int ks = 0; ks < 4; ++ks) {
        bf16x8 a = *(const bf16x8*)(aptr + ks * 64);
#pragma unroll
        for (int n = 0; n < 8; ++n) {
            bf16x8 b = *(const bf16x8*)(bptr + n * 16 * APITCH + ks * 64);
            acc[n] = __builtin_amdgcn_mfma_f32_16x16x32_bf16(a, b, acc[n], 0, 0, 0);
        }
    }

    // epilogue: dinv scale -> bf16 -> LDS (reuse A region) -> chunked store
    float dv[4];
    int rbase = row0 + w * 16 + l4 * 4;
#pragma unroll
    for (int j = 0; j < 4; ++j)
        dv[j] = (rbase + j < NN) ? dinv[rbase + j] : 0.f;
    unsigned short* ep = (unsigned short*)Ab;
#pragma unroll
    for (int n = 0; n < 8; ++n)
#pragma unroll
        for (int j = 0; j < 4; ++j)
            ep[(w * 16 + l4 * 4 + j) * 136 + n * 16 + l15] = f2bf(dv[j] * acc[n][j]);
    __syncthreads();
    int r = lane >> 2, part = lane & 3;
    int grow = row0 + w * 16 + r;
    if (grow < NN) {
        const char* lp = Ab + (w * 16 + r) * APITCH + part * 8;
#pragma unroll
        for (int c = 0; c < 8; ++c) {
            uint2 v = *(const uint2*)(lp + c * 32);
            *(uint2*)(HS + (size_t)c * CSTRIDE + (size_t)grow * 8 + part * 2) = v;
        }
    }
}

// -------- edge aggregation: chunked gather (per-XCD L2-resident) ----------
// blockIdx % 8 = chunk -> pinned to one XCD by round-robin dispatch.
// 32 nodes/block, 8 lanes/node (u = uint in chunk). hs pre-scaled by dinv:
// out[i,ch] = dinv[i]*( sum_e hs[src,ch] + hs[i,ch] ) + bias[ch]
// 8-deep MLP unroll: 8 independent 32B gathers in flight per lane-group.

__global__ __launch_bounds__(256) void aggregate_k(const uint32* __restrict__ hv,
                                                   const int* __restrict__ offs,
                                                   const int* __restrict__ csrc,
                                                   const float* __restrict__ dinv,
                                                   const float* __restrict__ bias,
                                                   uint32* __restrict__ out) {
    int t = threadIdx.x;
    int chunk = blockIdx.x & 7;
    int tile = blockIdx.x >> 3;
    int g = t >> 3, u = t & 7;
    int node = tile * 32 + g;                 // NN % 32 == 0, always valid
    const uint32* hc = hv + (size_t)chunk * CSTRIDE;
    int beg = offs[node], end = offs[node + 1];
    float di = dinv[node];
    uint32 sv = hc[(size_t)node * 8 + u];     // self (pre-scaled)
    float a0 = bflo(sv), a1 = bfhi(sv);
    int e = beg;
    for (; e + 7 < end; e += 8) {
        int s0 = __builtin_nontemporal_load(csrc + e + 0);
        int s1 = __builtin_nontemporal_load(csrc + e + 1);
        int s2 = __builtin_nontemporal_load(csrc + e + 2);
        int s3 = __builtin_nontemporal_load(csrc + e + 3);
        int s4 = __builtin_nontemporal_load(csrc + e + 4);
        int s5 = __builtin_nontemporal_load(csrc + e + 5);
        int s6 = __builtin_nontemporal_load(csrc + e + 6);
        int s7 = __builtin_nontemporal_load(csrc + e + 7);
        uint32 v0 = hc[(size_t)s0 * 8 + u];
        uint32 v1 = hc[(size_t)s1 * 8 + u];
        uint32 v2 = hc[(size_t)s2 * 8 + u];
        uint32 v3 = hc[(size_t)s3 * 8 + u];
        uint32 v4 = hc[(size_t)s4 * 8 + u];
        uint32 v5 = hc[(size_t)s5 * 8 + u];
        uint32 v6 = hc[(size_t)s6 * 8 + u];
        uint32 v7 = hc[(size_t)s7 * 8 + u];
        a0 += ((bflo(v0) + bflo(v1)) + (bflo(v2) + bflo(v3)))
            + ((bflo(v4) + bflo(v5)) + (bflo(v6) + bflo(v7)));
        a1 += ((bfhi(v0) + bfhi(v1)) + (bfhi(v2) + bfhi(v3)))
            + ((bfhi(v4) + bfhi(v5)) + (bfhi(v6) + bfhi(v7)));
    }
    for (; e + 3 < end; e += 4) {
        int s0 = __builtin_nontemporal_load(csrc + e + 0);
        int s1 = __builtin_nontemporal_load(csrc + e + 1);
        int s2 = __builtin_nontemporal_load(csrc + e + 2);
        int s3 = __builtin_nontemporal_load(csrc + e + 3);
        uint32 v0 = hc[(size_t)s0 * 8 + u];
        uint32 v1 = hc[(size_t)s1 * 8 + u];
        uint32 v2 = hc[(size_t)s2 * 8 + u];
        uint32 v3 = hc[(size_t)s3 * 8 + u];
        a0 += (bflo(v0) + bflo(v1)) + (bflo(v2) + bflo(v3));
        a1 += (bfhi(v0) + bfhi(v1)) + (bfhi(v2) + bfhi(v3));
    }
    for (; e < end; ++e) {
        int s0 = __builtin_nontemporal_load(csrc + e);
        uint32 v0 = hc[(size_t)s0 * 8 + u];
        a0 += bflo(v0);
        a1 += bfhi(v0);
    }
    float2 bb = ((const float2*)bias)[chunk * 8 + u];
    float o0 = fmaf(di, a0, bb.x);
    float o1 = fmaf(di, a1, bb.y);
    uint32 pk = (uint32)f2bf(o0) | ((uint32)f2bf(o1) << 16);
    __builtin_nontemporal_store(pk, out + (size_t)node * 64 + chunk * 8 + u);
}

// ---------------- GraphNorm stats over packed-bf16 activations ------------

__global__ __launch_bounds__(256) void colstats_k(const uint32* __restrict__ A,
                                                  float* __restrict__ stats) {
    __shared__ float4 sh[256];
    int t = threadIdx.x;
    int cp = t & 63;
    float s0 = 0.f, s1 = 0.f, q0 = 0.f, q1 = 0.f;
    for (int r = blockIdx.x * 4 + (t >> 6); r < NN; r += gridDim.x * 4) {
        uint32 u = A[(size_t)r * 64 + cp];
        float v0 = bflo(u), v1 = bfhi(u);
        s0 += v0; s1 += v1;
        q0 = fmaf(v0, v0, q0); q1 = fmaf(v1, v1, q1);
    }
    sh[t] = make_float4(s0, s1, q0, q1);
    __syncthreads();
    if (t < 128) {
        float4 a = sh[t], b = sh[t + 128];
        sh[t] = make_float4(a.x + b.x, a.y + b.y, a.z + b.z, a.w + b.w);
    }
    __syncthreads();
    if (t < 64) {
        float4 a = sh[t], b = sh[t + 64];
        atomicAdd(&stats[2 * cp], a.x + b.x);
        atomicAdd(&stats[2 * cp + 1], a.y + b.y);
        atomicAdd(&stats[128 + 2 * cp], a.z + b.z);
        atomicAdd(&stats[128 + 2 * cp + 1], a.w + b.w);
    }
}

__global__ void gnparams_k(const float* __restrict__ stats, const float* __restrict__ w,
                           const float* __restrict__ b, const float* __restrict__ a,
                           float* __restrict__ par) {
    int c = threadIdx.x;
    if (c < 128) {
        float m = stats[c] * (1.0f / NN);
        float ex2 = stats[128 + c] * (1.0f / NN);
        float ac = a[c];
        // var of (x - a*m): E[x^2] - 2*a*m^2 + a^2*m^2
        float var = ex2 - 2.0f * ac * m * m + ac * ac * m * m;
        float sc = w[c] * rsqrtf(var + 1e-5f);
        par[c] = sc;                       // scale
        par[128 + c] = b[c] - sc * ac * m; // shift
    }
}

// ---------------- head: out = [x, relu(gn2(x2))] @ Wh + bh ----------------

__global__ __launch_bounds__(256) void final_k(const float* __restrict__ x,
                                               const uint32* __restrict__ x2,
                                               const float* __restrict__ par,
                                               const float* __restrict__ Wh,
                                               const float* __restrict__ bh,
                                               float* __restrict__ out) {
    __shared__ float wl[256][16];
    int t = threadIdx.x;
    for (int i = t; i < 256 * 16; i += 256) wl[i >> 4][i & 15] = Wh[i];
    __syncthreads();
    int row = blockIdx.x * 16 + (t >> 4);
    int o = t & 15;
    if (row >= NN) return;
    const float4* xp = (const float4*)(x + (size_t)row * 128);
    const uint4* x2p = (const uint4*)(x2 + (size_t)row * 64);
    float acc = bh[o];
#pragma unroll
    for (int k4 = 0; k4 < 32; ++k4) {
        float4 v = xp[k4];
        acc = fmaf(v.x, wl[k4 * 4 + 0][o], acc);
        acc = fmaf(v.y, wl[k4 * 4 + 1][o], acc);
        acc = fmaf(v.z, wl[k4 * 4 + 2][o], acc);
        acc = fmaf(v.w, wl[k4 * 4 + 3][o], acc);
    }
#pragma unroll
    for (int k8 = 0; k8 < 16; ++k8) {
        uint4 u = x2p[k8];
        int c = k8 * 8;
        float v0 = bflo(u.x), v1 = bfhi(u.x);
        float v2 = bflo(u.y), v3 = bfhi(u.y);
        float v4 = bflo(u.z), v5 = bfhi(u.z);
        float v6 = bflo(u.w), v7 = bfhi(u.w);
        v0 = fmaxf(0.f, fmaf(par[c + 0], v0, par[128 + c + 0]));
        v1 = fmaxf(0.f, fmaf(par[c + 1], v1, par[128 + c + 1]));
        v2 = fmaxf(0.f, fmaf(par[c + 2], v2, par[128 + c + 2]));
        v3 = fmaxf(0.f, fmaf(par[c + 3], v3, par[128 + c + 3]));
        v4 = fmaxf(0.f, fmaf(par[c + 4], v4, par[128 + c + 4]));
        v5 = fmaxf(0.f, fmaf(par[c + 5], v5, par[128 + c + 5]));
        v6 = fmaxf(0.f, fmaf(par[c + 6], v6, par[128 + c + 6]));
        v7 = fmaxf(0.f, fmaf(par[c + 7], v7, par[128 + c + 7]));
        acc = fmaf(v0, wl[128 + c + 0][o], acc);
        acc = fmaf(v1, wl[128 + c + 1][o], acc);
        acc = fmaf(v2, wl[128 + c + 2][o], acc);
        acc = fmaf(v3, wl[128 + c + 3][o], acc);
        acc = fmaf(v4, wl[128 + c + 4][o], acc);
        acc = fmaf(v5, wl[128 + c + 5][o], acc);
        acc = fmaf(v6, wl[128 + c + 6][o], acc);
        acc = fmaf(v7, wl[128 + c + 7][o], acc);
    }
    out[(size_t)row * 16 + o] = acc;
}

// ---------------- launch ----------------

extern "C" void kernel_launch(void* const* d_in, const int* in_sizes, int n_in,
                              void* d_out, int out_size, void* d_ws, size_t ws_size,
                              hipStream_t stream) {
    const float* x   = (const float*)d_in[0];
    const int*   ei  = (const int*)d_in[1];
    const float* W1  = (const float*)d_in[2];
    const float* b1  = (const float*)d_in[3];
    const float* g1w = (const float*)d_in[4];
    const float* g1b = (const float*)d_in[5];
    const float* g1a = (const float*)d_in[6];
    const float* W2  = (const float*)d_in[7];
    const float* b2  = (const float*)d_in[8];
    const float* g2w = (const float*)d_in[9];
    const float* g2b = (const float*)d_in[10];
    const float* g2a = (const float*)d_in[11];
    const float* Wh  = (const float*)d_in[12];
    const float* bh  = (const float*)d_in[13];
    const int* srcp = ei;        // edge_index row 0
    const int* dstp = ei + NE;   // edge_index row 1
    float* out = (float*)d_out;

    char* p = (char*)d_ws;
    auto take = [&](size_t bytes) { char* r = p; p += (bytes + 255) & ~(size_t)255; return r; };
    int*   histT  = (int*)take((size_t)256 * NBLK * 4);
    int*   boff2  = (int*)take((size_t)256 * NBLK * 4);
    int*   btot   = (int*)take(256 * 4);
    int*   bucket_base = (int*)take(257 * 4);
    uint32* ebuf  = (uint32*)take((size_t)NE * 4);
    int*   offs   = (int*)take((size_t)(NN + 1) * 4);
    int*   csrc   = (int*)take((size_t)NE * 4);
    float* dinv   = (float*)take((size_t)NN * 4);
    float* stats1 = (float*)take(256 * 4);
    float* stats2 = (float*)take(256 * 4);
    float* par1   = (float*)take(256 * 4);
    float* par2   = (float*)take(256 * 4);
    uint32* wt1   = (uint32*)take((size_t)128 * 64 * 4);   // bf16 W1^T
    uint32* wt2   = (uint32*)take((size_t)128 * 64 * 4);   // bf16 W2^T
    uint32* bufH  = (uint32*)take((size_t)NN * 64 * 4);    // bf16, chunked
    uint32* bufA  = (uint32*)take((size_t)NN * 64 * 4);    // bf16 packed

    hipMemsetAsync(stats1, 0, 256 * 4, stream);
    hipMemsetAsync(stats2, 0, 256 * 4, stream);

    // CSR build (atomic-free, streaming)
    p1_hist_k<<<NBLK, 256, 0, stream>>>(dstp, histT);
    p2a_k<<<256, 256, 0, stream>>>(histT, boff2, btot);
    p2b_k<<<1, 256, 0, stream>>>(btot, bucket_base, offs);
    p3_scatter_k<<<NBLK, 256, 0, stream>>>(srcp, dstp, boff2, bucket_base, ebuf);
    p4_csr_k<<<NBUCK, 256, 0, stream>>>(ebuf, bucket_base, offs, dinv, csrc);

    // weight prep (bf16 transpose)
    wprep_k<<<32, 256, 0, stream>>>(W1, wt1);
    wprep_k<<<32, 256, 0, stream>>>(W2, wt2);

    const int AGG_GRID = (NN / 32) * 8;   // 3125 tiles x 8 chunks

    // layer 1: h1 = dinv * (x @ W1) (bf16 MFMA, chunked), aggregate, stats
    gemm_k<0><<<(NN + 63) / 64, 256, 0, stream>>>(x, wt1, nullptr, dinv, bufH);
    aggregate_k<<<AGG_GRID, 256, 0, stream>>>(bufH, offs, csrc, dinv, b1, bufA);
    colstats_k<<<512, 256, 0, stream>>>(bufA, stats1);
    gnparams_k<<<1, 128, 0, stream>>>(stats1, g1w, g1b, g1a, par1);

    // layer 2: h2 = dinv * (relu(gn1(bufA)) @ W2), aggregate, stats
    gemm_k<1><<<(NN + 63) / 64, 256, 0, stream>>>(bufA, wt2, par1, dinv, bufH);
    aggregate_k<<<AGG_GRID, 256, 0, stream>>>(bufH, offs, csrc, dinv, b2, bufA);
    colstats_k<<<512, 256, 0, stream>>>(bufA, stats2);
    gnparams_k<<<1, 128, 0, stream>>>(stats2, g2w, g2b, g2a, par2);

    // head: out = [x, relu(gn2(bufA))] @ Wh + bh (gn2 fused on load)
    final_k<<<(NN + 15) / 16, 256, 0, stream>>>(x, bufA, par2, Wh, bh, out);
}

// Round 11
// 323.225 us; speedup vs baseline: 1.6627x; 1.6627x over previous
//
#include <hip/hip_runtime.h>

#define NN 100000
#define NE 1600000

#define EBLK 4096
#define NBLK 391            // ceil(NE/EBLK)
#define NBUCK 196           // ceil(NN/512), bucket = dst>>9
#define AGG_BLOCKS 3125     // 32 nodes per block

typedef unsigned int uint32;
typedef __attribute__((ext_vector_type(8))) short bf16x8;
typedef __attribute__((ext_vector_type(4))) float f32x4;

__device__ inline unsigned short f2bf(float f) {
    uint32 u = __float_as_uint(f);
    u += 0x7FFFu + ((u >> 16) & 1u);      // round to nearest even
    return (unsigned short)(u >> 16);
}
__device__ inline float bflo(uint32 v) { return __uint_as_float(v << 16); }
__device__ inline float bfhi(uint32 v) { return __uint_as_float(v & 0xFFFF0000u); }

__device__ inline int wave_incl_scan(int v) {   // 64-lane inclusive scan
#pragma unroll
    for (int d = 1; d < 64; d <<= 1) {
        int u = __shfl_up(v, d, 64);
        if ((threadIdx.x & 63) >= (unsigned)d) v += u;
    }
    return v;
}

// ---------------- CSR build, atomic-free (bucketed) ----------------

__global__ __launch_bounds__(256) void p1_hist_k(const int* __restrict__ dst,
                                                 int* __restrict__ histT) {
    __shared__ int h[256];
    int t = threadIdx.x;
    h[t] = 0;
    __syncthreads();
    int e0 = blockIdx.x * EBLK;
#pragma unroll
    for (int i = 0; i < EBLK / 256; ++i) {
        int e = e0 + i * 256 + t;
        if (e < NE) atomicAdd(&h[dst[e] >> 9], 1);
    }
    __syncthreads();
    histT[t * NBLK + blockIdx.x] = h[t];   // histT[bucket][blk]
}

__global__ __launch_bounds__(256) void p2a_k(const int* __restrict__ histT,
                                             int* __restrict__ boff2,
                                             int* __restrict__ btot) {
    __shared__ int ws[4];
    __shared__ int ws2[4];
    int b = blockIdx.x, t = threadIdx.x;
    const int* row = histT + (size_t)b * NBLK;
    int v0 = row[t];
    int i0 = wave_incl_scan(v0);
    if ((t & 63) == 63) ws[t >> 6] = i0;
    __syncthreads();
    int add = 0;
    for (int w = 0; w < (t >> 6); ++w) add += ws[w];
    boff2[(size_t)b * NBLK + t] = i0 - v0 + add;
    int tot0 = ws[0] + ws[1] + ws[2] + ws[3];
    int idx = 256 + t;
    int v1 = (idx < NBLK) ? row[idx] : 0;
    int i1 = wave_incl_scan(v1);
    if ((t & 63) == 63) ws2[t >> 6] = i1;
    __syncthreads();
    int add2 = 0;
    for (int w = 0; w < (t >> 6); ++w) add2 += ws2[w];
    if (idx < NBLK) boff2[(size_t)b * NBLK + idx] = tot0 + i1 - v1 + add2;
    if (t == 0) btot[b] = tot0 + ws2[0] + ws2[1] + ws2[2] + ws2[3];
}

__global__ __launch_bounds__(256) void p2b_k(const int* __restrict__ btot,
                                             int* __restrict__ bucket_base,
                                             int* __restrict__ offs) {
    __shared__ int ws[4];
    int t = threadIdx.x;
    int v = btot[t];
    int incl = wave_incl_scan(v);
    if ((t & 63) == 63) ws[t >> 6] = incl;
    __syncthreads();
    int add = 0;
    for (int w = 0; w < (t >> 6); ++w) add += ws[w];
    int excl = incl - v + add;
    bucket_base[t] = excl;
    if (t == 255) bucket_base[256] = excl + v;   // == NE
    if (t == 0) offs[NN] = NE;
}

__global__ __launch_bounds__(256) void p3_scatter_k(const int* __restrict__ src,
                                                    const int* __restrict__ dst,
                                                    const int* __restrict__ boff2,
                                                    const int* __restrict__ bucket_base,
                                                    uint32* __restrict__ ebuf) {
    __shared__ int cur[256];
    int t = threadIdx.x;
    cur[t] = bucket_base[t] + boff2[(size_t)t * NBLK + blockIdx.x];
    __syncthreads();
    int e0 = blockIdx.x * EBLK;
#pragma unroll
    for (int i = 0; i < EBLK / 256; ++i) {
        int e = e0 + i * 256 + t;
        if (e < NE) {
            int d = dst[e];
            int pos = atomicAdd(&cur[d >> 9], 1);      // LDS atomic
            ebuf[pos] = ((uint32)(d & 511) << 17) | (uint32)src[e];
        }
    }
}

__global__ __launch_bounds__(256) void p4_csr_k(const uint32* __restrict__ ebuf,
                                                const int* __restrict__ bucket_base,
                                                int* __restrict__ offs,
                                                float* __restrict__ dinv,
                                                int* __restrict__ csrc) {
    __shared__ int cntL[512];
    __shared__ int offL[512];
    __shared__ int wsum[4];
    int t = threadIdx.x;
    int bbase = bucket_base[blockIdx.x];
    int bend  = bucket_base[blockIdx.x + 1];
    cntL[t] = 0; cntL[t + 256] = 0;
    __syncthreads();
    for (int e = bbase + t; e < bend; e += 256)
        atomicAdd(&cntL[ebuf[e] >> 17], 1);
    __syncthreads();
    int c0 = cntL[2 * t], c1 = cntL[2 * t + 1];
    int ps = c0 + c1;
    int incl = wave_incl_scan(ps);
    if ((t & 63) == 63) wsum[t >> 6] = incl;
    __syncthreads();
    int add = 0;
    for (int w = 0; w < (t >> 6); ++w) add += wsum[w];
    int excl = incl - ps + add;
    offL[2 * t] = excl;
    offL[2 * t + 1] = excl + c0;
    int n0 = blockIdx.x * 512;
#pragma unroll
    for (int j = 0; j < 2; ++j) {
        int dl = 2 * t + j;
        int node = n0 + dl;
        if (node < NN) {
            offs[node] = bbase + offL[dl];
            dinv[node] = rsqrtf((float)(cntL[dl] + 1));
        }
    }
    __syncthreads();
    cntL[2 * t] = offL[2 * t];          // reuse as cursors
    cntL[2 * t + 1] = offL[2 * t + 1];
    __syncthreads();
    for (int e = bbase + t; e < bend; e += 256) {
        uint32 v = ebuf[e];
        int pos = atomicAdd(&cntL[v >> 17], 1);   // LDS atomic
        csrc[bbase + pos] = (int)(v & 0x1FFFFu);
    }
}

// -------- W prep (both weights): Wt[col][k] bf16-packed ----------

__global__ __launch_bounds__(256) void wprep_k(const float* __restrict__ W1,
                                               const float* __restrict__ W2,
                                               uint32* __restrict__ wt1,
                                               uint32* __restrict__ wt2) {
    int id = blockIdx.x * 256 + threadIdx.x;   // 16384
    const float* W = (id < 8192) ? W1 : W2;
    uint32* Wt = (id < 8192) ? wt1 : wt2;
    int i = id & 8191;
    int col = i >> 6, ku = i & 63;
    float a = W[(2 * ku) * 128 + col];
    float b = W[(2 * ku + 1) * 128 + col];
    Wt[i] = (uint32)f2bf(a) | ((uint32)f2bf(b) << 16);
}

// ---------------- MFMA GEMM: HS[N,128](bf16) = dinv * act(X) @ W ----------
// AFF=0: X f32 [N,128]. AFF=1: X packed bf16; GraphNorm params computed
// in-block from stats (sum/sumsq) + (gw,gb,ga), relu(sc*x+sh) on load.
// Block: 256 thr / 4 waves, tile 64 rows x 128 cols, K=128 in 4 steps of 32.

template <int AFF>
__global__ __launch_bounds__(256) void gemm_k(const void* __restrict__ Xv,
                                              const uint32* __restrict__ Wt,
                                              const float* __restrict__ stats,
                                              const float* __restrict__ gw,
                                              const float* __restrict__ gb,
                                              const float* __restrict__ ga,
                                              const float* __restrict__ dinv,
                                              uint32* __restrict__ HS) {
    __shared__ __align__(16) char lds[52224];
    __shared__ float parL[256];
    const int APITCH = 272;               // bytes per A/B row (136 bf16)
    char* Ab = lds;
    char* Bb = lds + 17408;
    int t = threadIdx.x;
    int row0 = blockIdx.x * 64;

    if (AFF) {
        if (t < 128) {
            float m = stats[t] * (1.0f / NN);
            float ex2 = stats[128 + t] * (1.0f / NN);
            float ac = ga[t];
            float var = ex2 - 2.0f * ac * m * m + ac * ac * m * m;
            float sc = gw[t] * rsqrtf(var + 1e-5f);
            parL[t] = sc;
            parL[128 + t] = gb[t] - sc * ac * m;
        }
        __syncthreads();
    }

    // stage Bt: 128 rows x 16 uint4
    {
        uint4* src = (uint4*)Wt;
#pragma unroll
        for (int i = 0; i < 8; ++i) {
            int idx4 = i * 256 + t;          // 2048 uint4
            int r = idx4 >> 4, cu = idx4 & 15;
            *(uint4*)(Bb + r * APITCH + cu * 16) = src[r * 16 + cu];
        }
    }
    // stage A: 64 rows x 128 bf16
#pragma unroll
    for (int i = 0; i < 8; ++i) {
        int idx = i * 256 + t;               // 2048 quads of channels
        int r = idx >> 5, c4 = idx & 31;
        int row = row0 + r;
        float4 v = make_float4(0.f, 0.f, 0.f, 0.f);
        if (row < NN) {
            if (AFF) {
                uint2 u = *((const uint2*)((const uint32*)Xv + (size_t)row * 64) + c4);
                v.x = bflo(u.x); v.y = bfhi(u.x);
                v.z = bflo(u.y); v.w = bfhi(u.y);
                int c = c4 * 4;
                v.x = fmaxf(0.f, fmaf(parL[c + 0], v.x, parL[128 + c + 0]));
                v.y = fmaxf(0.f, fmaf(parL[c + 1], v.y, parL[128 + c + 1]));
                v.z = fmaxf(0.f, fmaf(parL[c + 2], v.z, parL[128 + c + 2]));
                v.w = fmaxf(0.f, fmaf(parL[c + 3], v.w, parL[128 + c + 3]));
            } else {
                v = *((const float4*)((const float*)Xv + (size_t)row * 128) + c4);
            }
        }
        uint32 o0 = (uint32)f2bf(v.x) | ((uint32)f2bf(v.y) << 16);
        uint32 o1 = (uint32)f2bf(v.z) | ((uint32)f2bf(v.w) << 16);
        uint2 o; o.x = o0; o.y = o1;
        *(uint2*)(Ab + r * APITCH + c4 * 8) = o;
    }
    __syncthreads();

    int w = t >> 6, lane = t & 63;
    int l15 = lane & 15, l4 = lane >> 4;
    const char* aptr = Ab + (w * 16 + l15) * APITCH + l4 * 16;
    const char* bptr = Bb + l15 * APITCH + l4 * 16;
    f32x4 acc[8];
#pragma unroll
    for (int n = 0; n < 8; ++n)
#pragma unroll
        for (int j = 0; j < 4; ++j) acc[n][j] = 0.f;

#pragma unroll
    for (int ks = 0; ks < 4; ++ks) {
        bf16x8 a = *(const bf16x8*)(aptr + ks * 64);
#pragma unroll
        for (int n = 0; n < 8; ++n) {
            bf16x8 b = *(const bf16x8*)(bptr + n * 16 * APITCH + ks * 64);
            acc[n] = __builtin_amdgcn_mfma_f32_16x16x32_bf16(a, b, acc[n], 0, 0, 0);
        }
    }

    // epilogue: dinv scale -> bf16 -> LDS (reuse A region) -> coalesced store
    float dv[4];
    int rbase = row0 + w * 16 + l4 * 4;
#pragma unroll
    for (int j = 0; j < 4; ++j)
        dv[j] = (rbase + j < NN) ? dinv[rbase + j] : 0.f;
    unsigned short* ep = (unsigned short*)Ab;
#pragma unroll
    for (int n = 0; n < 8; ++n)
#pragma unroll
        for (int j = 0; j < 4; ++j)
            ep[(w * 16 + l4 * 4 + j) * 136 + n * 16 + l15] = f2bf(dv[j] * acc[n][j]);
    __syncthreads();
    int srow = lane >> 2, seg = lane & 3;
    int grow = row0 + w * 16 + srow;
    if (grow < NN) {
        const char* lp = Ab + (w * 16 + srow) * APITCH + seg * 64;
        uint4* gp = (uint4*)(HS + (size_t)grow * 64 + seg * 16);   // seg*16 uints!
#pragma unroll
        for (int i = 0; i < 4; ++i)
            gp[i] = *(const uint4*)(lp + i * 16);
    }
}

// ---------------- edge aggregation + fused GraphNorm stats ----------------
// hs rows pre-scaled by dinv:
// out[i,c] = dinv[i]*( sum_e hs[src,c] + hs[i,c] ) + bias[c]   (bf16 packed)
// One wave per node, 8 nodes sequentially per wave (32 nodes/block).
// Lane owns channels {2*lane, 2*lane+1}. 16-deep MLP unroll.
// Per-thread stats regs -> cross-wave LDS reduce -> pstats[block][256].

__global__ __launch_bounds__(256) void aggregate_k(const uint32* __restrict__ hv,
                                                   const int* __restrict__ offs,
                                                   const int* __restrict__ csrc,
                                                   const float* __restrict__ dinv,
                                                   const float* __restrict__ bias,
                                                   uint32* __restrict__ out,
                                                   float* __restrict__ pstats) {
    __shared__ float4 sh[256];
    int t = threadIdx.x;
    int w = t >> 6, lane = t & 63;
    int nbase = blockIdx.x * 32 + w * 8;
    float2 bb = ((const float2*)bias)[lane];
    float s0 = 0.f, s1 = 0.f, q0 = 0.f, q1 = 0.f;
#pragma unroll 1
    for (int i = 0; i < 8; ++i) {
        int node = nbase + i;
        int beg = offs[node], end = offs[node + 1];
        float di = dinv[node];
        uint32 sv = hv[(size_t)node * 64 + lane];   // self (pre-scaled)
        float a0 = bflo(sv), a1 = bfhi(sv);
        int e = beg;
        for (; e + 15 < end; e += 16) {
            int x0 = csrc[e + 0], x1 = csrc[e + 1], x2 = csrc[e + 2], x3 = csrc[e + 3];
            int x4 = csrc[e + 4], x5 = csrc[e + 5], x6 = csrc[e + 6], x7 = csrc[e + 7];
            int x8 = csrc[e + 8], x9 = csrc[e + 9], xa = csrc[e + 10], xb = csrc[e + 11];
            int xc = csrc[e + 12], xd = csrc[e + 13], xe = csrc[e + 14], xf = csrc[e + 15];
            uint32 v0 = hv[(size_t)x0 * 64 + lane];
            uint32 v1 = hv[(size_t)x1 * 64 + lane];
            uint32 v2 = hv[(size_t)x2 * 64 + lane];
            uint32 v3 = hv[(size_t)x3 * 64 + lane];
            uint32 v4 = hv[(size_t)x4 * 64 + lane];
            uint32 v5 = hv[(size_t)x5 * 64 + lane];
            uint32 v6 = hv[(size_t)x6 * 64 + lane];
            uint32 v7 = hv[(size_t)x7 * 64 + lane];
            uint32 v8 = hv[(size_t)x8 * 64 + lane];
            uint32 v9 = hv[(size_t)x9 * 64 + lane];
            uint32 va = hv[(size_t)xa * 64 + lane];
            uint32 vb = hv[(size_t)xb * 64 + lane];
            uint32 vc = hv[(size_t)xc * 64 + lane];
            uint32 vd = hv[(size_t)xd * 64 + lane];
            uint32 ve = hv[(size_t)xe * 64 + lane];
            uint32 vf = hv[(size_t)xf * 64 + lane];
            a0 += (((bflo(v0) + bflo(v1)) + (bflo(v2) + bflo(v3)))
                 + ((bflo(v4) + bflo(v5)) + (bflo(v6) + bflo(v7))))
                + (((bflo(v8) + bflo(v9)) + (bflo(va) + bflo(vb)))
                 + ((bflo(vc) + bflo(vd)) + (bflo(ve) + bflo(vf))));
            a1 += (((bfhi(v0) + bfhi(v1)) + (bfhi(v2) + bfhi(v3)))
                 + ((bfhi(v4) + bfhi(v5)) + (bfhi(v6) + bfhi(v7))))
                + (((bfhi(v8) + bfhi(v9)) + (bfhi(va) + bfhi(vb)))
                 + ((bfhi(vc) + bfhi(vd)) + (bfhi(ve) + bfhi(vf))));
        }
        for (; e + 3 < end; e += 4) {
            int x0 = csrc[e + 0], x1 = csrc[e + 1], x2 = csrc[e + 2], x3 = csrc[e + 3];
            uint32 v0 = hv[(size_t)x0 * 64 + lane];
            uint32 v1 = hv[(size_t)x1 * 64 + lane];
            uint32 v2 = hv[(size_t)x2 * 64 + lane];
            uint32 v3 = hv[(size_t)x3 * 64 + lane];
            a0 += (bflo(v0) + bflo(v1)) + (bflo(v2) + bflo(v3));
            a1 += (bfhi(v0) + bfhi(v1)) + (bfhi(v2) + bfhi(v3));
        }
        for (; e < end; ++e) {
            int x0 = csrc[e];
            uint32 v0 = hv[(size_t)x0 * 64 + lane];
            a0 += bflo(v0);
            a1 += bfhi(v0);
        }
        float o0 = fmaf(di, a0, bb.x);
        float o1 = fmaf(di, a1, bb.y);
        out[(size_t)node * 64 + lane] = (uint32)f2bf(o0) | ((uint32)f2bf(o1) << 16);
        s0 += o0; s1 += o1;
        q0 = fmaf(o0, o0, q0); q1 = fmaf(o1, o1, q1);
    }
    sh[t] = make_float4(s0, s1, q0, q1);
    __syncthreads();
    if (t < 128) {
        float4 a = sh[t], b = sh[t + 128];
        sh[t] = make_float4(a.x + b.x, a.y + b.y, a.z + b.z, a.w + b.w);
    }
    __syncthreads();
    if (t < 64) {
        float4 a = sh[t], b = sh[t + 64];
        float* ps = pstats + (size_t)blockIdx.x * 256;
        ps[2 * t] = a.x + b.x;
        ps[2 * t + 1] = a.y + b.y;
        ps[128 + 2 * t] = a.z + b.z;
        ps[128 + 2 * t + 1] = a.w + b.w;
    }
}

// ---------------- stats reduction: pstats[3125][256] -> stats[256] --------

__global__ __launch_bounds__(256) void red_k(const float* __restrict__ pstats,
                                             float* __restrict__ stats) {
    int t = threadIdx.x;
    float s = 0.f;
    for (int r = blockIdx.x; r < AGG_BLOCKS; r += 64)
        s += pstats[(size_t)r * 256 + t];
    atomicAdd(&stats[t], s);
}

// ---------------- head: out = [x, relu(gn2(x2))] @ Wh + bh ----------------

__global__ __launch_bounds__(256) void final_k(const float* __restrict__ x,
                                               const uint32* __restrict__ x2,
                                               const float* __restrict__ stats,
                                               const float* __restrict__ gw,
                                               const float* __restrict__ gb,
                                               const float* __restrict__ ga,
                                               const float* __restrict__ Wh,
                                               const float* __restrict__ bh,
                                               float* __restrict__ out) {
    __shared__ float wl[256][16];
    __shared__ float parL[256];
    int t = threadIdx.x;
    if (t < 128) {
        float m = stats[t] * (1.0f / NN);
        float ex2 = stats[128 + t] * (1.0f / NN);
        float ac = ga[t];
        float var = ex2 - 2.0f * ac * m * m + ac * ac * m * m;
        float sc = gw[t] * rsqrtf(var + 1e-5f);
        parL[t] = sc;
        parL[128 + t] = gb[t] - sc * ac * m;
    }
    for (int i = t; i < 256 * 16; i += 256) wl[i >> 4][i & 15] = Wh[i];
    __syncthreads();
    int row = blockIdx.x * 16 + (t >> 4);
    int o = t & 15;
    if (row >= NN) return;
    const float4* xp = (const float4*)(x + (size_t)row * 128);
    const uint4* x2p = (const uint4*)(x2 + (size_t)row * 64);
    float acc = bh[o];
#pragma unroll
    for (int k4 = 0; k4 < 32; ++k4) {
        float4 v = xp[k4];
        acc = fmaf(v.x, wl[k4 * 4 + 0][o], acc);
        acc = fmaf(v.y, wl[k4 * 4 + 1][o], acc);
        acc = fmaf(v.z, wl[k4 * 4 + 2][o], acc);
        acc = fmaf(v.w, wl[k4 * 4 + 3][o], acc);
    }
#pragma unroll
    for (int k8 = 0; k8 < 16; ++k8) {
        uint4 u = x2p[k8];
        int c = k8 * 8;
        float v0 = bflo(u.x), v1 = bfhi(u.x);
        float v2 = bflo(u.y), v3 = bfhi(u.y);
        float v4 = bflo(u.z), v5 = bfhi(u.z);
        float v6 = bflo(u.w), v7 = bfhi(u.w);
        v0 = fmaxf(0.f, fmaf(parL[c + 0], v0, parL[128 + c + 0]));
        v1 = fmaxf(0.f, fmaf(parL[c + 1], v1, parL[128 + c + 1]));
        v2 = fmaxf(0.f, fmaf(parL[c + 2], v2, parL[128 + c + 2]));
        v3 = fmaxf(0.f, fmaf(parL[c + 3], v3, parL[128 + c + 3]));
        v4 = fmaxf(0.f, fmaf(parL[c + 4], v4, parL[128 + c + 4]));
        v5 = fmaxf(0.f, fmaf(parL[c + 5], v5, parL[128 + c + 5]));
        v6 = fmaxf(0.f, fmaf(parL[c + 6], v6, parL[128 + c + 6]));
        v7 = fmaxf(0.f, fmaf(parL[c + 7], v7, parL[128 + c + 7]));
        acc = fmaf(v0, wl[128 + c + 0][o], acc);
        acc = fmaf(v1, wl[128 + c + 1][o], acc);
        acc = fmaf(v2, wl[128 + c + 2][o], acc);
        acc = fmaf(v3, wl[128 + c + 3][o], acc);
        acc = fmaf(v4, wl[128 + c + 4][o], acc);
        acc = fmaf(v5, wl[128 + c + 5][o], acc);
        acc = fmaf(v6, wl[128 + c + 6][o], acc);
        acc = fmaf(v7, wl[128 + c + 7][o], acc);
    }
    out[(size_t)row * 16 + o] = acc;
}

// ---------------- launch ----------------

extern "C" void kernel_launch(void* const* d_in, const int* in_sizes, int n_in,
                              void* d_out, int out_size, void* d_ws, size_t ws_size,
                              hipStream_t stream) {
    const float* x   = (const float*)d_in[0];
    const int*   ei  = (const int*)d_in[1];
    const float* W1  = (const float*)d_in[2];
    const float* b1  = (const float*)d_in[3];
    const float* g1w = (const float*)d_in[4];
    const float* g1b = (const float*)d_in[5];
    const float* g1a = (const float*)d_in[6];
    const float* W2  = (const float*)d_in[7];
    const float* b2  = (const float*)d_in[8];
    const float* g2w = (const float*)d_in[9];
    const float* g2b = (const float*)d_in[10];
    const float* g2a = (const float*)d_in[11];
    const float* Wh  = (const float*)d_in[12];
    const float* bh  = (const float*)d_in[13];
    const int* srcp = ei;        // edge_index row 0
    const int* dstp = ei + NE;   // edge_index row 1
    float* out = (float*)d_out;

    char* p = (char*)d_ws;
    auto take = [&](size_t bytes) { char* r = p; p += (bytes + 255) & ~(size_t)255; return r; };
    int*   histT  = (int*)take((size_t)256 * NBLK * 4);
    int*   boff2  = (int*)take((size_t)256 * NBLK * 4);
    int*   btot   = (int*)take(256 * 4);
    int*   bucket_base = (int*)take(257 * 4);
    uint32* ebuf  = (uint32*)take((size_t)NE * 4);
    int*   offs   = (int*)take((size_t)(NN + 1) * 4);
    int*   csrc   = (int*)take((size_t)NE * 4);
    float* dinv   = (float*)take((size_t)NN * 4);
    float* pstats = (float*)take((size_t)AGG_BLOCKS * 256 * 4);
    float* stats1 = (float*)take(256 * 4);
    float* stats2 = (float*)take(256 * 4);
    uint32* wt1   = (uint32*)take((size_t)128 * 64 * 4);   // bf16 W1^T
    uint32* wt2   = (uint32*)take((size_t)128 * 64 * 4);   // bf16 W2^T
    uint32* bufH  = (uint32*)take((size_t)NN * 64 * 4);    // bf16 packed
    uint32* bufA  = (uint32*)take((size_t)NN * 64 * 4);    // bf16 packed

    hipMemsetAsync(stats1, 0, 256 * 4, stream);
    hipMemsetAsync(stats2, 0, 256 * 4, stream);

    // CSR build (atomic-free, streaming)
    p1_hist_k<<<NBLK, 256, 0, stream>>>(dstp, histT);
    p2a_k<<<256, 256, 0, stream>>>(histT, boff2, btot);
    p2b_k<<<1, 256, 0, stream>>>(btot, bucket_base, offs);
    p3_scatter_k<<<NBLK, 256, 0, stream>>>(srcp, dstp, boff2, bucket_base, ebuf);
    p4_csr_k<<<NBUCK, 256, 0, stream>>>(ebuf, bucket_base, offs, dinv, csrc);

    // weight prep (bf16 transpose, both layers)
    wprep_k<<<64, 256, 0, stream>>>(W1, W2, wt1, wt2);

    // layer 1: h1 = dinv * (x @ W1) (bf16 MFMA), aggregate+stats, reduce
    gemm_k<0><<<(NN + 63) / 64, 256, 0, stream>>>(x, wt1, nullptr, nullptr, nullptr,
                                                  nullptr, dinv, bufH);
    aggregate_k<<<AGG_BLOCKS, 256, 0, stream>>>(bufH, offs, csrc, dinv, b1, bufA, pstats);
    red_k<<<64, 256, 0, stream>>>(pstats, stats1);

    // layer 2: h2 = dinv * (relu(gn1(bufA)) @ W2) (gn1 computed in-block)
    gemm_k<1><<<(NN + 63) / 64, 256, 0, stream>>>(bufA, wt2, stats1, g1w, g1b, g1a,
                                                  dinv, bufH);
    aggregate_k<<<AGG_BLOCKS, 256, 0, stream>>>(bufH, offs, csrc, dinv, b2, bufA, pstats);
    red_k<<<64, 256, 0, stream>>>(pstats, stats2);

    // head: out = [x, relu(gn2(bufA))] @ Wh + bh (gn2 computed in-block)
    final_k<<<(NN + 15) / 16, 256, 0, stream>>>(x, bufA, stats2, g2w, g2b, g2a,
                                                Wh, bh, out);
}